// Round 5
// baseline (449.232 us; speedup 1.0000x reference)
//
#include <hip/hip_runtime.h>

// FastQuantumAttention: per-token 32x32 head-mixing attention, MFMA bf16 path.
// 1 wave = 1 token. B*L = 16384 tokens, D = 4096 = 32 heads x 128.

typedef __attribute__((ext_vector_type(8)))  __bf16      bf16x8;
typedef __attribute__((ext_vector_type(16))) float        f32x16;
typedef __attribute__((ext_vector_type(4)))  unsigned int uint4v;

static __device__ __forceinline__ unsigned int bfbits(float f) {
    // float -> bf16 bits, round-to-nearest-even
    unsigned int u = __float_as_uint(f);
    return (u + 0x7FFFu + ((u >> 16) & 1u)) >> 16;
}
static __device__ __forceinline__ unsigned int pack2bf(float lo, float hi) {
    return bfbits(lo) | (bfbits(hi) << 16);
}

#define LDS_STRIDE 136   // u16 per row: 128 + 8 pad (272 B, 16B-aligned rows)

__global__ __launch_bounds__(256) void fqa_kernel(const float* __restrict__ x,
                                                  const float* __restrict__ pat,
                                                  float* __restrict__ out,
                                                  int T) {
    __shared__ __align__(16) unsigned short lds[4][32][LDS_STRIDE];

    const int lane = threadIdx.x & 63;
    const int wv   = threadIdx.x >> 6;
    const int tok  = blockIdx.x * 4 + wv;
    if (tok >= T) return;

    const float* xrow = x   + (size_t)tok * 4096;
    float*       orow = out + (size_t)tok * 4096;

    const int h  = lane & 31;      // head owned by this lane (A/B frag row/col)
    const int hi = lane >> 5;      // lane half
    const int d0 = hi << 3;        // k-offset within 16-wide K step

    // ---- 1. load x row (strided gather covering every byte once), apply
    //         patterns in f32, convert to bf16 fragments ----
    uint4v frag[8];
#pragma unroll
    for (int k = 0; k < 8; ++k) {
        const int off = h * 128 + d0 + (k << 4);
        const float4 xa = *reinterpret_cast<const float4*>(xrow + off);
        const float4 xb = *reinterpret_cast<const float4*>(xrow + off + 4);
        const float4 pa = *reinterpret_cast<const float4*>(pat + off);
        const float4 pb = *reinterpret_cast<const float4*>(pat + off + 4);
        frag[k].x = pack2bf(xa.x * pa.x, xa.y * pa.y);
        frag[k].y = pack2bf(xa.z * pa.z, xa.w * pa.w);
        frag[k].z = pack2bf(xb.x * pb.x, xb.y * pb.y);
        frag[k].w = pack2bf(xb.z * pb.z, xb.w * pb.w);
    }

    // ---- 2. stage xh into LDS (row = head, col = d), for the PV transpose ----
#pragma unroll
    for (int k = 0; k < 8; ++k) {
        *reinterpret_cast<uint4v*>(&lds[wv][h][d0 + (k << 4)]) = frag[k];
    }

    // ---- 3. S = xh . xh^T  (A == B -> bitwise-symmetric result) ----
    f32x16 acc = {0,0,0,0, 0,0,0,0, 0,0,0,0, 0,0,0,0};
#pragma unroll
    for (int k = 0; k < 8; ++k) {
        const bf16x8 af = __builtin_bit_cast(bf16x8, frag[k]);
        acc = __builtin_amdgcn_mfma_f32_32x32x16_bf16(af, af, acc, 0, 0, 0);
    }

    // ---- 4. softmax along the row(reg) axis (valid because S symmetric):
    //         lane holds column n = lane&31; rows split with lane^32 partner ----
    const float C = 0.12754245006530176f;  // (1/sqrt(128)) * log2(e)
    float mx = acc[0];
#pragma unroll
    for (int i = 1; i < 16; ++i) mx = fmaxf(mx, acc[i]);
    mx = fmaxf(mx, __shfl_xor(mx, 32));

    float p[16];
    float s = 0.f;
#pragma unroll
    for (int i = 0; i < 16; ++i) { p[i] = exp2f((acc[i] - mx) * C); s += p[i]; }
    s += __shfl_xor(s, 32);
    const float rden = 1.0f / s;

    // pack P to bf16x2, swap halves, assemble PV A-fragments (K=32 in 2 steps)
    unsigned int pk[8], sw[8];
#pragma unroll
    for (int j = 0; j < 8; ++j) pk[j] = pack2bf(p[2 * j] * rden, p[2 * j + 1] * rden);
#pragma unroll
    for (int j = 0; j < 8; ++j) sw[j] = __shfl_xor(pk[j], 32);

    const bool lo_half = (hi == 0);
    uint4v P0u, P1u;
    P0u.x = lo_half ? pk[0] : sw[2];
    P0u.y = lo_half ? pk[1] : sw[3];
    P0u.z = lo_half ? sw[0] : pk[2];
    P0u.w = lo_half ? sw[1] : pk[3];
    P1u.x = lo_half ? pk[4] : sw[6];
    P1u.y = lo_half ? pk[5] : sw[7];
    P1u.z = lo_half ? sw[4] : pk[6];
    P1u.w = lo_half ? sw[5] : pk[7];
    const bf16x8 P0 = __builtin_bit_cast(bf16x8, P0u);
    const bf16x8 P1 = __builtin_bit_cast(bf16x8, P1u);

    // ---- 5. out = P . xh, 4 tiles of 32 d-columns; store each tile at once ----
    const int col = lane & 31;  // d within tile
#pragma unroll
    for (int nt = 0; nt < 4; ++nt) {
        f32x16 o = {0,0,0,0, 0,0,0,0, 0,0,0,0, 0,0,0,0};

        // ks = 0  (g = d0 .. d0+7)
        {
            unsigned int v0 = lds[wv][d0 + 0][nt * 32 + col];
            unsigned int v1 = lds[wv][d0 + 1][nt * 32 + col];
            unsigned int v2 = lds[wv][d0 + 2][nt * 32 + col];
            unsigned int v3 = lds[wv][d0 + 3][nt * 32 + col];
            unsigned int v4 = lds[wv][d0 + 4][nt * 32 + col];
            unsigned int v5 = lds[wv][d0 + 5][nt * 32 + col];
            unsigned int v6 = lds[wv][d0 + 6][nt * 32 + col];
            unsigned int v7 = lds[wv][d0 + 7][nt * 32 + col];
            uint4v bu;
            bu.x = v0 | (v1 << 16);
            bu.y = v2 | (v3 << 16);
            bu.z = v4 | (v5 << 16);
            bu.w = v6 | (v7 << 16);
            o = __builtin_amdgcn_mfma_f32_32x32x16_bf16(P0, __builtin_bit_cast(bf16x8, bu), o, 0, 0, 0);
        }
        // ks = 1  (g = 16+d0 .. 16+d0+7)
        {
            unsigned int v0 = lds[wv][16 + d0 + 0][nt * 32 + col];
            unsigned int v1 = lds[wv][16 + d0 + 1][nt * 32 + col];
            unsigned int v2 = lds[wv][16 + d0 + 2][nt * 32 + col];
            unsigned int v3 = lds[wv][16 + d0 + 3][nt * 32 + col];
            unsigned int v4 = lds[wv][16 + d0 + 4][nt * 32 + col];
            unsigned int v5 = lds[wv][16 + d0 + 5][nt * 32 + col];
            unsigned int v6 = lds[wv][16 + d0 + 6][nt * 32 + col];
            unsigned int v7 = lds[wv][16 + d0 + 7][nt * 32 + col];
            uint4v bu;
            bu.x = v0 | (v1 << 16);
            bu.y = v2 | (v3 << 16);
            bu.z = v4 | (v5 << 16);
            bu.w = v6 | (v7 << 16);
            o = __builtin_amdgcn_mfma_f32_32x32x16_bf16(P1, __builtin_bit_cast(bf16x8, bu), o, 0, 0, 0);
        }

#pragma unroll
        for (int r = 0; r < 16; ++r) {
            const int hh = (r & 3) + ((r >> 2) << 3) + (hi << 2);  // verified C/D row map
            orow[hh * 128 + nt * 32 + col] = o[r];
        }
    }
}

extern "C" void kernel_launch(void* const* d_in, const int* in_sizes, int n_in,
                              void* d_out, int out_size, void* d_ws, size_t ws_size,
                              hipStream_t stream) {
    const float* x   = (const float*)d_in[0];
    const float* pat = (const float*)d_in[1];
    float*       out = (float*)d_out;
    const int T = in_sizes[0] / 4096;          // B*L tokens
    const int blocks = (T + 3) / 4;            // 4 tokens (waves) per block
    hipLaunchKernelGGL(fqa_kernel, dim3(blocks), dim3(256), 0, stream, x, pat, out, T);
}